// Round 1
// baseline (155.653 us; speedup 1.0000x reference)
//
#include <hip/hip_runtime.h>

// DeepClusterLoss: out[0]=total, out[1]=recon_loss, out[2]=cluster_loss
// recon_loss = sum((recon_x - x)^2)   over [N=1e6, D=64] f32
// cluster_loss = sum((x - centers[assign])^2)
// ALPHA = BETA = 1.0

#define NROWS 1000000
#define DCOLS 64
#define KCLUST 100
#define BLOCK 256
#define GRID 2048

__global__ void dcl_zero_out(float* __restrict__ out) {
    out[0] = 0.0f;
    out[1] = 0.0f;
    out[2] = 0.0f;
}

__global__ __launch_bounds__(BLOCK) void dcl_main(
    const float* __restrict__ recon_x,
    const float* __restrict__ x,
    const int* __restrict__ assign,
    const float* __restrict__ centers,
    float* __restrict__ out)
{
    __shared__ float lds_centers[KCLUST * DCOLS];  // 25.6 KB
    for (int i = threadIdx.x; i < KCLUST * DCOLS; i += BLOCK) {
        lds_centers[i] = centers[i];
    }
    __syncthreads();

    const int t  = threadIdx.x;
    const int r  = t >> 4;        // row within 16-row group: 0..15
    const int lr = t & 15;        // float4 slot within row: 0..15
    const int col = lr * 4;

    float racc = 0.0f;            // recon partial
    float cacc = 0.0f;            // cluster partial

    const int total_groups = NROWS / 16;  // 62500, exact (no tail)
    for (int g = blockIdx.x; g < total_groups; g += gridDim.x) {
        const int row = g * 16 + r;
        const int c = assign[row];
        const long long base = (long long)row * DCOLS + col;

        const float4 xv = *reinterpret_cast<const float4*>(x + base);
        const float4 rv = *reinterpret_cast<const float4*>(recon_x + base);
        const float4 cv = *reinterpret_cast<const float4*>(&lds_centers[c * DCOLS + col]);

        float d0 = rv.x - xv.x;
        float d1 = rv.y - xv.y;
        float d2 = rv.z - xv.z;
        float d3 = rv.w - xv.w;
        racc += d0 * d0 + d1 * d1 + d2 * d2 + d3 * d3;

        float e0 = xv.x - cv.x;
        float e1 = xv.y - cv.y;
        float e2 = xv.z - cv.z;
        float e3 = xv.w - cv.w;
        cacc += e0 * e0 + e1 * e1 + e2 * e2 + e3 * e3;
    }

    // wave-64 butterfly reduce
    #pragma unroll
    for (int off = 32; off > 0; off >>= 1) {
        racc += __shfl_down(racc, off);
        cacc += __shfl_down(cacc, off);
    }

    __shared__ float wsum_r[BLOCK / 64];
    __shared__ float wsum_c[BLOCK / 64];
    const int wave = t >> 6;
    if ((t & 63) == 0) {
        wsum_r[wave] = racc;
        wsum_c[wave] = cacc;
    }
    __syncthreads();

    if (t == 0) {
        float R = 0.0f, C = 0.0f;
        #pragma unroll
        for (int w = 0; w < BLOCK / 64; ++w) { R += wsum_r[w]; C += wsum_c[w]; }
        atomicAdd(&out[1], R);
        atomicAdd(&out[2], C);
        atomicAdd(&out[0], R + C);   // ALPHA=BETA=1
    }
}

extern "C" void kernel_launch(void* const* d_in, const int* in_sizes, int n_in,
                              void* d_out, int out_size, void* d_ws, size_t ws_size,
                              hipStream_t stream) {
    const float* recon_x = (const float*)d_in[0];
    const float* x       = (const float*)d_in[1];
    const int*   assign  = (const int*)d_in[2];
    const float* centers = (const float*)d_in[3];
    float* out = (float*)d_out;

    dcl_zero_out<<<1, 1, 0, stream>>>(out);
    dcl_main<<<GRID, BLOCK, 0, stream>>>(recon_x, x, assign, centers, out);
}